// Round 1
// 109.672 us; speedup vs baseline: 1.0114x; 1.0114x over previous
//
#include <hip/hip_runtime.h>

#define HW   112
#define PH   114            // padded plane dim
#define KK   576
#define ROWB (PH * 128)                    // bytes per padded NHWC row
#define PLANE_SH (8 * PH * PH * 64)        // shorts per power plane
#define PLANE_B  (PLANE_SH * 2)            // bytes per plane
#define WB_OFF_SH (3 * PLANE_SH)
#define S_OFF_SH  (WB_OFF_SH + 36864)
// ws_size needed: ~40 MB

typedef __attribute__((ext_vector_type(8))) short s16x8;
typedef __attribute__((ext_vector_type(4))) float f32x4;
typedef __attribute__((ext_vector_type(2))) float f32x2;
typedef __attribute__((address_space(3))) unsigned int lds_u32;
typedef const __attribute__((address_space(1))) unsigned int glb_u32;

__device__ inline unsigned short f2bf(float f) {
    unsigned u = __float_as_uint(f);
    u += 0x7FFF + ((u >> 16) & 1);            // RNE
    return (unsigned short)(u >> 16);
}

// ---- pass 1 (fused): pow planes + border zeros + weight transpose + row sums ----
// Wb flat index: (((tap*2 + cc)*4 + nt)*64 + lane)*8 + j
//   k = cc*32 + (lane>>4)*8 + j, n = nt*16 + (lane&15), value = W[n][k*9 + tap]
__global__ __launch_bounds__(256) void prep_pow(const float* __restrict__ img,
                                                const float* __restrict__ W,
                                                unsigned short* __restrict__ pw,
                                                unsigned short* __restrict__ wb,
                                                float* __restrict__ S) {
    __shared__ __align__(16) unsigned short sA[3 * 112 * 72];   // [p][x][c pad 72]
    const int bid = blockIdx.x, t = threadIdx.x;
    if (bid < 896) {                         // pow: 8b * 112y
        const int b = bid / 112, y = bid - b * 112;
        const int c = t & 63, xq0 = t >> 6;
        const float4* src = (const float4*)(img + (((size_t)(b * 64 + c) * HW + y) * HW));
        #pragma unroll
        for (int i = 0; i < 7; ++i) {
            const int xq = xq0 + i * 4;
            const float4 v = src[xq];
            const float vv[4] = {v.x, v.y, v.z, v.w};
            #pragma unroll
            for (int u = 0; u < 4; ++u) {
                const float v1 = vv[u], v2 = v1 * v1, v3 = v2 * v1;
                const int x = xq * 4 + u;
                sA[x * 72 + c]         = f2bf(v1);
                sA[8064 + x * 72 + c]  = f2bf(v2);
                sA[16128 + x * 72 + c] = f2bf(v3);
            }
        }
        __syncthreads();
        for (int i = 0; i < 11; ++i) {
            const int ch = t + i * 256;
            if (ch >= 2688) break;           // 3p * 112x * 8 c-octs
            const int p = ch / 896, r = ch - p * 896;
            const int x = r >> 3, c8 = r & 7;
            const s16x8 val = *(const s16x8*)&sA[p * 8064 + x * 72 + c8 * 8];
            *(s16x8*)&pw[(size_t)p * PLANE_SH + ((size_t)(b * PH + y + 1) * PH + (x + 1)) * 64 + c8 * 8] = val;
        }
    } else if (bid < 920) {                  // border zeros: 3p * 8b
        const int k = bid - 896;
        const int p = k >> 3, b = k & 7;
        unsigned short* base = pw + (size_t)p * PLANE_SH + (size_t)b * PH * PH * 64;
        const s16x8 z = {0, 0, 0, 0, 0, 0, 0, 0};
        for (int i = 0; i < 15; ++i) {
            const int e = t + i * 256;
            if (e >= 3616) break;            // 452 border px * 8 c-octs
            const int n = e >> 3, c8 = e & 7;
            int x, yy;
            if (n < 114)      { yy = 0;   x = n; }
            else if (n < 228) { yy = 113; x = n - 114; }
            else { const int m2 = n - 228; yy = 1 + (m2 >> 1); x = (m2 & 1) ? 113 : 0; }
            *(s16x8*)&base[(yy * PH + x) * 64 + c8 * 8] = z;
        }
    } else if (bid < 1064) {                 // weight transpose: 144 blocks
        const int i   = (bid - 920) * 256 + t;
        const int j   = i & 7;
        const int l   = (i >> 3) & 63;
        const int nt  = (i >> 9) & 3;
        const int cc  = (i >> 11) & 1;
        const int tap = i >> 12;
        const int c   = cc * 32 + ((l >> 4) << 3) + j;
        const int o   = nt * 16 + (l & 15);
        wb[i] = f2bf(W[o * KK + c * 9 + tap]);
    } else {                                 // row sums
        __shared__ float partial[256];
        const int o = t >> 2, part = t & 3;
        const float4* row = (const float4*)(W + o * KK) + part * 36;
        float s = 0.f;
        for (int k = 0; k < 36; ++k) { float4 v = row[k]; s += v.x + v.y + v.z + v.w; }
        partial[t] = s;
        __syncthreads();
        if (part == 0) S[o] = partial[t] + partial[t + 1] + partial[t + 2] + partial[t + 3];
    }
}

// ---- pass 2: conv, 6-phase (cc x plane) double-buffered pipeline ----
// block = 256 thr (4 waves), tile = 8 rows x 16 px x 32 oc; wave wv: rows 2wv, 2wv+1
// A LDS per phase: one plane, one cc-half: [row 10][px 18][c8s 4] granules,
//   swizzle c8s = c8 ^ (px&3) ^ ((px>>2)&3); double-buffered (2 x 11,520 B)
// W: NOT in LDS -- each wave loads its 18 B-fragments (this oc-half, this cc)
//   straight from L2-resident wb into registers, once per cc.
// Pipeline: counted vmcnt(3) per phase (3 wave-uniform global_load_lds per phase),
//   A(pb) issued 2 phases ahead of use; vmcnt drains to 0 only at the tail.
#define LP_ROW   1152                      // 18 px * 64 B
#define LP_PHASE 11520                     // 10 rows * LP_ROW

__global__ __launch_bounds__(256, 3) void conv_main(const unsigned short* __restrict__ pw,
                                                    const unsigned short* __restrict__ wb,
                                                    const float* __restrict__ S,
                                                    float* __restrict__ out) {
    __shared__ __align__(16) char tile[2 * LP_PHASE];   // 23,040 B -> 3 blocks/CU

    const int t = threadIdx.x, wv = t >> 6, lane = t & 63;
    const int m = lane & 15, q = lane >> 4;

    const int bid = blockIdx.x;       // 1568: b = bid&7 (XCD pin); oc-half pairs adjacent
    const int b = bid & 7;
    const int rest = bid >> 3;        // 0..195
    const int oc2 = rest & 1;
    const int r = rest >> 1;          // 0..97 = 14 ty * 7 tx
    const int ty = r / 7, tx = r - ty * 7;
    const int y0 = ty * 8, x0 = tx * 16;

    f32x4 acc[3][2][2];               // [power][at][ntl]
    #pragma unroll
    for (int p = 0; p < 3; ++p)
        #pragma unroll
        for (int at = 0; at < 2; ++at)
            #pragma unroll
            for (int ntl = 0; ntl < 2; ++ntl)
                acc[p][at][ntl] = (f32x4){0.f, 0.f, 0.f, 0.f};

    const char* pwin  = (const char*)pw + ((size_t)(b * PH + y0) * PH + x0) * 128;
    const char* wbase = (const char*)wb + oc2 * 2048 + lane * 16;

    s16x8 bfr[9][2];                  // this cc's B fragments, in registers (72 VGPR)

    // byte offset of W chunk (tap, cc, ntl) for our oc-half:
    //   ((tap*2+cc)*4 + oc2*2 + ntl)*1024 = (tap*2+cc)*4096 + oc2*2048 + ntl*1024
    auto loadW = [&](int cc) {
        #pragma unroll
        for (int tap = 0; tap < 9; ++tap)
            #pragma unroll
            for (int ntl = 0; ntl < 2; ++ntl)
                bfr[tap][ntl] = *(const s16x8*)(wbase + (tap * 2 + cc) * 4096 + ntl * 1024);
    };

    // stage one (cc, plane) A sub-tile into buf; exactly 3 global_load_lds per wave
    auto stageA = [&](int cc, int p, int buf) {
        #pragma unroll
        for (int i = 0; i < 3; ++i) {
            const int f = i * 4096 + t * 16;
            if (f < LP_PHASE) {
                const int row = f / LP_ROW;
                const int r2  = f - row * LP_ROW;
                const int px  = r2 >> 6;
                const int c8s = (r2 >> 4) & 3;
                const int c8  = c8s ^ (px & 3) ^ ((px >> 2) & 3);
                const char* gp = pwin + (size_t)p * PLANE_B + row * ROWB + px * 128 + cc * 64 + c8 * 16;
                lds_u32* lp = (lds_u32*)(tile + buf * LP_PHASE + i * 4096 + wv * 1024);
                __builtin_amdgcn_global_load_lds((glb_u32*)gp, lp, 16, 0, 0);
            }
        }
    };

    // prologue: W(cc0) first, then A0 -> buf0, A1 -> buf1  (18 + 3 + 3 in flight)
    loadW(0);
    __builtin_amdgcn_sched_barrier(0);
    stageA(0, 0, 0);
    stageA(0, 1, 1);
    __builtin_amdgcn_sched_barrier(0);

    #pragma unroll
    for (int pb = 0; pb < 6; ++pb) {
        const int p   = (pb < 3) ? pb : pb - 3;
        const int buf = pb & 1;

        // A(pb) is older than the 3 loads of A(pb+1) (and anything issued later),
        // so vmcnt(3) always guarantees A(pb) has landed; tail drains to 0.
        if (pb < 5) asm volatile("s_waitcnt vmcnt(3)" ::: "memory");
        else        asm volatile("s_waitcnt vmcnt(0)" ::: "memory");
        __builtin_amdgcn_sched_barrier(0);
        __builtin_amdgcn_s_barrier();
        __builtin_amdgcn_sched_barrier(0);

        const char* base = tile + buf * LP_PHASE;
        #pragma unroll
        for (int kx = 0; kx < 3; ++kx) {
            const int pxr  = m + kx;
            const int c8sr = q ^ (pxr & 3) ^ ((pxr >> 2) & 3);
            const int abase = wv * (2 * LP_ROW) + pxr * 64 + c8sr * 16;
            s16x8 af[4];
            #pragma unroll
            for (int r4 = 0; r4 < 4; ++r4)
                af[r4] = *(const s16x8*)&base[abase + r4 * LP_ROW];
            __builtin_amdgcn_s_setprio(1);
            #pragma unroll
            for (int ky = 0; ky < 3; ++ky)
                #pragma unroll
                for (int at = 0; at < 2; ++at)
                    #pragma unroll
                    for (int ntl = 0; ntl < 2; ++ntl)
                        acc[p][at][ntl] = __builtin_amdgcn_mfma_f32_16x16x32_bf16(
                            af[at + ky], bfr[ky * 3 + kx][ntl], acc[p][at][ntl], 0, 0, 0);
            __builtin_amdgcn_s_setprio(0);
        }

        __builtin_amdgcn_sched_barrier(0);
        __builtin_amdgcn_s_barrier();
        __builtin_amdgcn_sched_barrier(0);
        if (pb == 2) {                       // bfr(cc0) now dead; fetch cc1 fragments
            loadW(1);
            __builtin_amdgcn_sched_barrier(0);  // keep W1 older than A4 for vmcnt math
        }
        if (pb < 4) {                        // issue A(pb+2) into the buffer just freed
            const int pn = pb + 2;
            stageA((pn < 3) ? 0 : 1, (pn < 3) ? pn : pn - 3, buf);
        }
        __builtin_amdgcn_sched_barrier(0);
    }

    // ---- epilogue: telescoped diffs, f32x2 packed; D: n = lane&15, px = q*4+reg ----
    #pragma unroll
    for (int ntl = 0; ntl < 2; ++ntl) {
        const int o = (oc2 * 2 + ntl) * 16 + (lane & 15);
        const float Sv = S[o];
        const float fS = -0.000287f / 75.f * Sv;
        const float cg1 = 0.8448f  + 0.001309f * Sv;
        const float D1  = 0.52992f - 0.003809f * Sv;
        const float D2  = 0.45312f + 0.001546f * Sv;
        const float D3  = 1.152f   - 0.006386f * Sv;
        const float D4  = 0.91392f - 0.00283f  * Sv;
        #pragma unroll
        for (int at = 0; at < 2; ++at) {
            float res[4];
            #pragma unroll
            for (int h = 0; h < 2; ++h) {
                const f32x2 u1 = {acc[0][at][ntl][2 * h], acc[0][at][ntl][2 * h + 1]};
                const f32x2 u2 = {acc[1][at][ntl][2 * h], acc[1][at][ntl][2 * h + 1]};
                const f32x2 u3 = {acc[2][at][ntl][2 * h], acc[2][at][ntl][2 * h + 1]};
                const f32x2 f  = fS   + 0.00354667f * u1 - 0.00146267f * u2;
                const f32x2 g1 = cg1  + 0.00619f    * u1 - 0.009f      * u2 + 0.001383f * u3;
                const f32x2 d1 = D1   - 0.00316f    * u1 + 0.00416f    * u2 + 0.016117f * u3;
                const f32x2 d2 = D2   - 0.00116f    * u1 + 0.006717f   * u2 - 0.00248f  * u3;
                const f32x2 d3 = D3   - 0.000753f   * u1 + 0.005643f   * u2 - 0.00602f  * u3;
                const f32x2 d4 = D4   - 0.000691f   * u1 + 0.00085f    * u2 - 0.00487f  * u3;
                f32x2 E;
                E.x = __expf(-10.f * f.x);
                E.y = __expf(-10.f * f.y);
                const f32x2 den1 = 1.f + E * 4.4816890703f;
                const f32x2 den2 = 1.f + E * 9.9741824548f;
                const f32x2 den3 = 1.f + E * 24.5325301971f;
                const f32x2 den4 = 1.f + E * 49.4024491055f;
                f32x2 o2 = g1;
                o2.x += __builtin_amdgcn_rcpf(den1.x) * d1.x + __builtin_amdgcn_rcpf(den2.x) * d2.x
                      + __builtin_amdgcn_rcpf(den3.x) * d3.x + __builtin_amdgcn_rcpf(den4.x) * d4.x;
                o2.y += __builtin_amdgcn_rcpf(den1.y) * d1.y + __builtin_amdgcn_rcpf(den2.y) * d2.y
                      + __builtin_amdgcn_rcpf(den3.y) * d3.y + __builtin_amdgcn_rcpf(den4.y) * d4.y;
                res[2 * h] = o2.x; res[2 * h + 1] = o2.y;
            }
            const int y = y0 + 2 * wv + at;
            float* op = out + (((size_t)(b * 64 + o)) * HW + y) * HW + x0 + q * 4;
            *(float4*)op = make_float4(res[0], res[1], res[2], res[3]);
        }
    }
}

extern "C" void kernel_launch(void* const* d_in, const int* in_sizes, int n_in,
                              void* d_out, int out_size, void* d_ws, size_t ws_size,
                              hipStream_t stream) {
    const float* img = (const float*)d_in[0];
    const float* w   = (const float*)d_in[1];
    float* outp = (float*)d_out;
    unsigned short* pw = (unsigned short*)d_ws;
    unsigned short* wb = pw + WB_OFF_SH;
    float* S = (float*)(pw + S_OFF_SH);

    hipLaunchKernelGGL(prep_pow,  dim3(1065), dim3(256), 0, stream, img, w, pw, wb, S);
    hipLaunchKernelGGL(conv_main, dim3(1568), dim3(256), 0, stream, pw, wb, S, outp);
}